// Round 5
// baseline (636.526 us; speedup 1.0000x reference)
//
#include <hip/hip_runtime.h>
#include <math.h>

// Problem constants (fixed by setup_inputs)
#define BN    4096
#define DD    1024
#define CC    1000
#define MM    32768
#define ROWS_CAP 32768   // worst-case B + mem_ptr

// A/B fp8 are stored CHUNK-MAJOR TILED (gemm-native):
//   addr(row, k) = (row>>7)*131072 + (k>>4)*2048 + (row&127)*16 + (k&15)
// conv writes this layout via an LDS transpose (coalesced both sides);
// gemm's global_load_lds source is linear in thread id (fully coalesced).

#define NGROUP_A 512            // ROWS_CAP / 64
#define NGROUP_B 16             // 1024 / 64
#define NCOUNT   512            // 4 col-blocks x 128 row-blocks
#define NBITS    512            // ROWS_CAP / 64 label-bitmask blocks

// fused-gemm partial state: 14 floats per (row, col-block, wn-half, k-half)
//   [0..9] top-10 negatives (descending), [10] pmax, [11] psum, [12] wsum, [13] wsim
// plane layout: partials[(k*NSUB + sub) * ROWS_CAP + row], sub = cb*4 + wn*2 + q
#define NSUB 32                 // 8 col-blocks x 2 wn-halves x 2 q-halves

typedef __attribute__((ext_vector_type(8))) int   int8v;
typedef __attribute__((ext_vector_type(16))) float f32x16;

__device__ __forceinline__ float wave_sum_f(float v) {
#pragma unroll
  for (int off = 32; off >= 1; off >>= 1) v += __shfl_xor(v, off, 64);
  return v;
}

__device__ __forceinline__ int pack4(float a, float b, float c, float d) {
  int p = __builtin_amdgcn_cvt_pk_fp8_f32(a, b, 0, false);
  p = __builtin_amdgcn_cvt_pk_fp8_f32(c, d, p, true);
  return p;
}

__device__ __forceinline__ void gload16(const unsigned char* g, unsigned char* l) {
  __builtin_amdgcn_global_load_lds(
      (const __attribute__((address_space(1))) unsigned int*)g,
      (__attribute__((address_space(3))) unsigned int*)l, 16, 0, 0);
}

// branchless sorted-descending top-10 insert: 1 fmax + 9 med3
__device__ __forceinline__ void ins10(float* t, float v) {
#pragma unroll
  for (int i = 9; i >= 1; --i) t[i] = __builtin_amdgcn_fmed3f(v, t[i - 1], t[i]);
  t[0] = fmaxf(t[0], v);
}

// ---------------------------------------------------------------- conv + count + bitmask
// Blocks [0, NGROUP_A): 64 enhanced rows -> A tiled fp8 (LDS transpose).
// Blocks [NGROUP_A, +NGROUP_B): 64 prompt rows -> B tiled fp8.
// Blocks [NGROUP_A+NGROUP_B, +NCOUNT): class-count partial sums (atomic).
// Blocks [NGROUP_A+NGROUP_B+NCOUNT, +NBITS): label bitmask (32 u32 per row).
__global__ __launch_bounds__(256) void conv_kernel(const float* __restrict__ img,
                                                   const float* __restrict__ prompts,
                                                   const float* __restrict__ mem,
                                                   const int* __restrict__ memptr,
                                                   unsigned char* __restrict__ A,
                                                   unsigned char* __restrict__ B,
                                                   const int* __restrict__ labels,
                                                   const int* __restrict__ mlabels,
                                                   int* __restrict__ counts,
                                                   unsigned* __restrict__ bitmask) {
  const int blk = blockIdx.x;
  const int t = threadIdx.x;
  const int lane = t & 63;
  const int wid = t >> 6;
  const int nrows = BN + memptr[0];
  const int padded = (nrows + 127) & ~127;

  if (blk >= NGROUP_A + NGROUP_B + NCOUNT) {   // ---- bitmask section
    const int bi = blk - (NGROUP_A + NGROUP_B + NCOUNT);
    const int rowBase = bi * 64;
    if (rowBase >= padded) return;
    for (int i = 0; i < 16; ++i) {
      const int row = rowBase + wid * 16 + i;
      if (row >= padded) continue;
      unsigned bits = 0;
      if (row < nrows) {
        const int* lr = (row < BN) ? labels + (size_t)row * CC
                                   : mlabels + (size_t)(row - BN) * CC;
        const int cbase = lane * 16;
#pragma unroll
        for (int g = 0; g < 4; ++g) {
          int c = cbase + g * 4;
          int4 l4;
          if (c + 3 < CC) l4 = *(const int4*)(lr + c);
          else {
            l4.x = (c < CC) ? lr[c] : 0;
            l4.y = (c + 1 < CC) ? lr[c + 1] : 0;
            l4.z = (c + 2 < CC) ? lr[c + 2] : 0;
            l4.w = (c + 3 < CC) ? lr[c + 3] : 0;
          }
          unsigned m = 0;
          if (l4.x > 0) m |= 1u;
          if (l4.y > 0) m |= 2u;
          if (l4.z > 0) m |= 4u;
          if (l4.w > 0) m |= 8u;
          bits |= m << (g * 4);
        }
      }
      // lane l holds bits for cols [l*16, l*16+16): pair into 32-bit words
      unsigned pair = __shfl_xor(bits, 1, 64);
      if (!(lane & 1)) bitmask[(size_t)row * 32 + (lane >> 1)] = bits | (pair << 16);
    }
    return;
  }

  if (blk >= NGROUP_A + NGROUP_B) {            // ---- count section
    const int ci = blk - (NGROUP_A + NGROUP_B);
    const int c = (ci & 3) * 256 + t;
    if (c >= CC) return;
    const int b0 = (ci >> 2) * 32;
    int s = 0;
#pragma unroll
    for (int b = 0; b < 32; ++b) s += labels[(size_t)(b0 + b) * CC + c];
    atomicAdd(&counts[c], s);
    return;
  }

  // ---- transpose-convert section (64-row group)
  __shared__ unsigned char tile[65536];        // 64 kc-stripes x 1024 B

  const bool isB = (blk >= NGROUP_A);
  const int g = isB ? (blk - NGROUP_A) : blk;
  const int rowBase = g * 64;
  if (!isB && rowBase >= padded) return;       // never read by gemm

  unsigned char* dstBase = (isB ? B : A)
      + (size_t)(rowBase >> 7) * 131072 + (size_t)(rowBase & 64) * 16;

  for (int i = 0; i < 16; ++i) {
    const int r = wid * 16 + i;                // row slot within group
    const int row = rowBase + r;
    const float* src = nullptr;
    float esc = 1.0f;
    bool needNorm = false;
    if (isB) {
      if (row < CC) { src = prompts + (size_t)row * DD; needNorm = true; esc = 10.0f; }
    } else {
      if (row < BN)         { src = img + (size_t)row * DD; needNorm = true; }
      else if (row < nrows) { src = mem + (size_t)(row - BN) * DD; }
    }
    int4 o = {0, 0, 0, 0};
    if (src) {
      const float4* s4 = (const float4*)src + lane * 4;   // 64B per lane (k = lane*16..)
      float4 a = s4[0], b = s4[1], c = s4[2], d = s4[3];
      float sc = esc;
      if (needNorm) {
        float ss = a.x * a.x + a.y * a.y + a.z * a.z + a.w * a.w
                 + b.x * b.x + b.y * b.y + b.z * b.z + b.w * b.w
                 + c.x * c.x + c.y * c.y + c.z * c.z + c.w * c.w
                 + d.x * d.x + d.y * d.y + d.z * d.z + d.w * d.w;
        ss = wave_sum_f(ss);
        sc = esc * rsqrtf(ss + 1e-24f);
      }
      o.x = pack4(a.x * sc, a.y * sc, a.z * sc, a.w * sc);
      o.y = pack4(b.x * sc, b.y * sc, b.z * sc, b.w * sc);
      o.z = pack4(c.x * sc, c.y * sc, c.z * sc, c.w * sc);
      o.w = pack4(d.x * sc, d.y * sc, d.z * sc, d.w * sc);
    }
    // stripe kc = lane, rotated slot (r+kc)&63 -> distinct chunks per lane
    *(int4*)(tile + lane * 1024 + (((r + lane) & 63) << 4)) = o;
  }
  __syncthreads();

#pragma unroll
  for (int p = 0; p < 16; ++p) {
    const int ochunk = p * 256 + t;            // kc = ochunk>>6 (wave-uniform), rl = lane
    const int kc = ochunk >> 6;
    const int rl = ochunk & 63;
    int4 v = *(const int4*)(tile + kc * 1024 + (((rl + kc) & 63) << 4));
    *(int4*)(dstBase + (size_t)kc * 2048 + rl * 16) = v;   // 1KB contiguous per wave
  }
}

// ---------------------------------------------------------------- fused MX-fp8 GEMM + epilogue
// 128x128 tile. OPERAND-SWAPPED MFMA: mfma(B_frag, A_frag) so that
//   D col (lane&31)  = A row  = sim ROW
//   D reg pattern    = B row  = sim COL  (col = (reg&3)+8*(reg>>2)+4*(lane>>5))
// Occupancy-targeted: __launch_bounds__(256,3) caps VGPR (~170) for 3 blocks/CU;
// labels come in as a precomputed bitmask (1 int4 per row, not 4KB of ints);
// epilogue is per-quadrant online-softmax so acc quadrants die progressively.
__global__ __launch_bounds__(256, 3) void gemm_fused(
    const unsigned char* __restrict__ A, const unsigned char* __restrict__ Bm,
    const unsigned* __restrict__ bitmask, const int* __restrict__ counts,
    const int* __restrict__ memptr, float* __restrict__ partials) {
  const int f = blockIdx.x;
  const int x = f & 7;
  const int s = f >> 3;
  const int cb = s & 7;
  const int rt = (s >> 3) * 8 + x;             // same-rt blocks share an XCD (f%8)

  const int nrows = BN + memptr[0];
  const int row0 = rt * 128;
  if (row0 >= nrows) return;
  const int c0 = cb * 128;

  __shared__ unsigned char As[16384];
  __shared__ unsigned char Bs[16384];
  __shared__ unsigned posbits[128][4];         // bit c: label(row, c0+c) > 0
  __shared__ float wcol[128];                  // normalized class weights for our cols
  __shared__ float wpart[4];

  const int t = threadIdx.x;
  const int lane = t & 63;
  const int wid = t >> 6;
  const int wm = (wid >> 1) * 64;
  const int wn = (wid & 1) * 64;

  // ---------- preamble: class weights (global normalizer) + bitmask load
  {
    float wv[4];
    float accw = 0.f;
#pragma unroll
    for (int i = 0; i < 4; ++i) {
      int c = t + i * 256;
      float w = 0.f;
      if (c < CC) {
        float cnt = (float)counts[c];
        float en = 1.0f - expf(cnt * logf(0.999f));   // 1 - BETA^cnt
        w = (1.0f - 0.999f) / (en + 1e-8f);
      }
      wv[i] = w;
      accw += w;
    }
    float sw = wave_sum_f(accw);
    if (lane == 0) wpart[wid] = sw;
    if (t < 128) {
      const int4 bm = *(const int4*)(bitmask + (size_t)(row0 + t) * 32 + cb * 4);
      posbits[t][0] = bm.x; posbits[t][1] = bm.y;
      posbits[t][2] = bm.z; posbits[t][3] = bm.w;
    }
    __syncthreads();
    float tot = wpart[0] + wpart[1] + wpart[2] + wpart[3];
    float scw = (float)CC / tot;
#pragma unroll
    for (int i = 0; i < 4; ++i) {
      int c = t + i * 256;
      if (c >= c0 && c < c0 + 128) wcol[c - c0] = wv[i] * scw;
    }
  }
  // wcol/posbits writes are ordered before readers by the K-loop barriers.

  // ---------- K loop (coalesced tiled staging; operand-swapped MFMA)
  const unsigned char* gaT = A + (size_t)row0 * DD;
  const unsigned char* gbT = Bm + (size_t)c0 * DD;
  unsigned char* lA = As + t * 16;
  unsigned char* lB = Bs + t * 16;

  f32x16 acc[2][2] = {};
  const int q = lane >> 5;
  const int rr = lane & 31;

  for (int k0 = 0; k0 < DD; k0 += 128) {
    const size_t kb = (size_t)k0 * 128;
#pragma unroll
    for (int p = 0; p < 4; ++p)
      gload16(gaT + kb + p * 4096 + t * 16, lA + p * 4096);
#pragma unroll
    for (int p = 0; p < 4; ++p)
      gload16(gbT + kb + p * 4096 + t * 16, lB + p * 4096);
    __syncthreads();
#pragma unroll
    for (int h = 0; h < 2; ++h) {
      int8v af[2], bfv[2];
      const int kc = h * 4 + q * 2;
#pragma unroll
      for (int mi = 0; mi < 2; ++mi) {
        const unsigned char* pa = As + kc * 2048 + (wm + mi * 32 + rr) * 16;
        int4 lo4 = *(const int4*)pa;
        int4 hi4 = *(const int4*)(pa + 2048);
        af[mi][0] = lo4.x; af[mi][1] = lo4.y; af[mi][2] = lo4.z; af[mi][3] = lo4.w;
        af[mi][4] = hi4.x; af[mi][5] = hi4.y; af[mi][6] = hi4.z; af[mi][7] = hi4.w;
      }
#pragma unroll
      for (int ni = 0; ni < 2; ++ni) {
        const unsigned char* pb = Bs + kc * 2048 + (wn + ni * 32 + rr) * 16;
        int4 lo4 = *(const int4*)pb;
        int4 hi4 = *(const int4*)(pb + 2048);
        bfv[ni][0] = lo4.x; bfv[ni][1] = lo4.y; bfv[ni][2] = lo4.z; bfv[ni][3] = lo4.w;
        bfv[ni][4] = hi4.x; bfv[ni][5] = hi4.y; bfv[ni][6] = hi4.z; bfv[ni][7] = hi4.w;
      }
      // SWAPPED: B as a-operand, A as b-operand -> sim row is lane-local
#pragma unroll
      for (int mi = 0; mi < 2; ++mi)
#pragma unroll
        for (int ni = 0; ni < 2; ++ni)
          acc[mi][ni] = __builtin_amdgcn_mfma_scale_f32_32x32x64_f8f6f4(
              bfv[ni], af[mi], acc[mi][ni], 0, 0, 0, 127, 0, 127);
    }
    __syncthreads();
  }

  // ---------- register-local epilogue: per-quadrant online softmax
  const int cl = lane & 31;
  const int wnb = wid & 1;
  const int sub = cb * 4 + wnb * 2 + q;        // UNIQUE per (col-block, wn-half, q-half)
#pragma unroll
  for (int mi = 0; mi < 2; ++mi) {
    const int rl = wm + mi * 32 + cl;          // local row 0..127
    const int row_g = row0 + rl;
    float t10[10];
#pragma unroll
    for (int i = 0; i < 10; ++i) t10[i] = -INFINITY;
    float m = -INFINITY, ssum = 0.f, wsum = 0.f, wsim = 0.f;
#pragma unroll
    for (int ni = 0; ni < 2; ++ni) {
      const unsigned bits = posbits[rl][(wn >> 5) + ni];
      f32x16 v = acc[mi][ni];
      float pq = -INFINITY;
      unsigned pb = 0;
#pragma unroll
      for (int reg = 0; reg < 16; ++reg) {
        const int ci = (reg & 3) + 8 * (reg >> 2) + 4 * q;   // col within 32-group
        const int cg = c0 + wn + ni * 32 + ci;
        const float val = v[reg];
        const bool cvalid = (cg < CC);
        const bool pos = cvalid && ((bits >> ci) & 1u);
        if (pos) {
          float w = wcol[wn + ni * 32 + ci];
          wsum += w;
          wsim += w * val;
          pq = fmaxf(pq, val);
          pb |= 1u << reg;
        }
        ins10(t10, (cvalid && !pos) ? val : -INFINITY);
      }
      if (pb) {                                 // fold quadrant into running (m, ssum)
        float ps = 0.f;
#pragma unroll
        for (int reg = 0; reg < 16; ++reg)
          ps += expf(((pb >> reg) & 1u) ? (v[reg] - pq) : -INFINITY);
        float m2 = fmaxf(m, pq);
        ssum = ssum * expf(m - m2) + ps * expf(pq - m2);   // expf(-inf)=0 handles init
        m = m2;
      }
    }
    // write 14-float partial state (plane-major for coalesced merge reads)
    float* pp = partials + (size_t)sub * ROWS_CAP + row_g;
#pragma unroll
    for (int k = 0; k < 10; ++k) pp[(size_t)k * NSUB * ROWS_CAP] = t10[k];
    pp[(size_t)10 * NSUB * ROWS_CAP] = m;
    pp[(size_t)11 * NSUB * ROWS_CAP] = ssum;
    pp[(size_t)12 * NSUB * ROWS_CAP] = wsum;
    pp[(size_t)13 * NSUB * ROWS_CAP] = wsim;
  }
}

// ---------------------------------------------------------------- merge partials -> per-row loss
__global__ __launch_bounds__(64) void merge_kernel(const float* __restrict__ partials,
                                                   const int* __restrict__ memptr,
                                                   float* __restrict__ lps_arr,
                                                   float* __restrict__ valid_arr) {
  const int row = blockIdx.x * 64 + threadIdx.x;
  const int nrows = BN + memptr[0];
  if (row >= nrows) {
    lps_arr[row] = 0.f;
    valid_arr[row] = 0.f;
    return;
  }
  float t10[10];
#pragma unroll
  for (int i = 0; i < 10; ++i) t10[i] = -INFINITY;
  float Mp = -INFINITY, psum = 0.f, wsum = 0.f, wsim = 0.f;
  for (int sub = 0; sub < NSUB; ++sub) {
    const float* pp = partials + (size_t)sub * ROWS_CAP + row;
#pragma unroll
    for (int j = 0; j < 10; ++j) {
      float v = pp[(size_t)j * NSUB * ROWS_CAP];
#pragma unroll
      for (int i = 9; i >= 1; --i) t10[i] = __builtin_amdgcn_fmed3f(v, t10[i - 1], t10[i]);
      t10[0] = fmaxf(t10[0], v);
    }
    float pm = pp[(size_t)10 * NSUB * ROWS_CAP];
    float ps = pp[(size_t)11 * NSUB * ROWS_CAP];
    wsum += pp[(size_t)12 * NSUB * ROWS_CAP];
    wsim += pp[(size_t)13 * NSUB * ROWS_CAP];
    if (ps > 0.f) {                            // pm finite here
      float m2 = fmaxf(Mp, pm);
      psum = psum * expf(Mp - m2) + ps * expf(pm - m2);   // expf(-inf - m2)=0
      Mp = m2;
    }
  }
  const float M = fmaxf(Mp, t10[0]);           // finite: every row has >=10 negatives
  float esum = 0.f;
#pragma unroll
  for (int j = 0; j < 10; ++j) esum += expf(t10[j] - M);
  if (psum > 0.f) esum += psum * expf(Mp - M);
  const float lse = M + logf(esum);
  const bool valid = (wsum > 0.f);
  const float lps = valid ? (wsum * lse - wsim) / (wsum + 1e-8f) : 0.f;
  const float mult = (row < BN) ? 2.f : 1.f;   // image rows appear twice in enhanced set
  lps_arr[row] = mult * lps;
  valid_arr[row] = valid ? mult : 0.f;
}

// ---------------------------------------------------------------- final reduce
__global__ __launch_bounds__(1024) void reduce_kernel(const float* __restrict__ lps_arr,
                                                      const float* __restrict__ valid_arr,
                                                      float* __restrict__ out) {
  const int t = threadIdx.x;
  const float4* l4 = (const float4*)lps_arr;
  const float4* v4 = (const float4*)valid_arr;
  float s1 = 0.f, s2 = 0.f;
#pragma unroll
  for (int i = 0; i < 8; ++i) {
    float4 a = l4[t + i * 1024];
    float4 b = v4[t + i * 1024];
    s1 += a.x + a.y + a.z + a.w;
    s2 += b.x + b.y + b.z + b.w;
  }
  s1 = wave_sum_f(s1);
  s2 = wave_sum_f(s2);
  __shared__ float p1[16], p2[16];
  if ((t & 63) == 0) { p1[t >> 6] = s1; p2[t >> 6] = s2; }
  __syncthreads();
  if (t == 0) {
    float a = 0.f, b = 0.f;
#pragma unroll
    for (int i = 0; i < 16; ++i) { a += p1[i]; b += p2[i]; }
    out[0] = a / fmaxf(b, 1.0f);
  }
}

// ---------------------------------------------------------------- launcher
extern "C" void kernel_launch(void* const* d_in, const int* in_sizes, int n_in,
                              void* d_out, int out_size, void* d_ws, size_t ws_size,
                              hipStream_t stream) {
  const float* img     = (const float*)d_in[0];
  const float* prompts = (const float*)d_in[1];
  const int*   labels  = (const int*)d_in[2];
  const float* mem     = (const float*)d_in[3];
  const int*   mlabels = (const int*)d_in[4];
  const int*   memptr  = (const int*)d_in[5];
  float* out = (float*)d_out;
  char* ws = (char*)d_ws;

  int*      counts  = (int*)(ws + 0);            // 1000 ints (8 KiB reserved)
  float*    lps_arr = (float*)(ws + 8192);       // 32768 f
  float*    val_arr = (float*)(ws + 139264);     // 32768 f
  unsigned* bitmask = (unsigned*)(ws + 270336);  // 32768 x 32 u32 = 4 MiB
  unsigned char* Bf8 = (unsigned char*)(ws + 4464640);   // 1024x1024 fp8 = 1 MiB
  unsigned char* Af8 = (unsigned char*)(ws + 5513216);   // 32768x1024 fp8 = 32 MiB
  float* partials = (float*)(ws + 5513216 + (size_t)ROWS_CAP * DD);  // 14*32*32768*4 = 58.7 MB

  hipMemsetAsync(ws, 0, 4096, stream);      // zero counts

  conv_kernel<<<NGROUP_A + NGROUP_B + NCOUNT + NBITS, 256, 0, stream>>>(
      img, prompts, mem, memptr, Af8, Bf8, labels, mlabels, counts, bitmask);

  gemm_fused<<<8 * (ROWS_CAP / 128), 256, 0, stream>>>(
      Af8, Bf8, bitmask, counts, memptr, partials);

  merge_kernel<<<ROWS_CAP / 64, 64, 0, stream>>>(partials, memptr, lps_arr, val_arr);

  reduce_kernel<<<1, 1024, 0, stream>>>(lps_arr, val_arr, out);
}

// Round 6
// 392.420 us; speedup vs baseline: 1.6221x; 1.6221x over previous
//
#include <hip/hip_runtime.h>
#include <math.h>

// Problem constants (fixed by setup_inputs)
#define BN    4096
#define DD    1024
#define CC    1000
#define MM    32768
#define ROWS_CAP 32768   // worst-case B + mem_ptr

// A/B fp8 are stored CHUNK-MAJOR TILED (gemm-native):
//   addr(row, k) = (row>>7)*131072 + (k>>4)*2048 + (row&127)*16 + (k&15)
// conv writes this layout via an LDS transpose (coalesced both sides);
// gemm's global_load_lds source is linear in thread id (fully coalesced).

#define NGROUP_A 512            // ROWS_CAP / 64
#define NGROUP_B 16             // 1024 / 64
#define NCOUNT   512            // 4 col-blocks x 128 row-blocks
#define NBITS    512            // ROWS_CAP / 64 label-bitmask blocks

// fused-gemm partial state: 14 floats per (row, col-block, wn-half, q-half)
//   [0..9] top-10 negatives (descending), [10] pmax, [11] psum, [12] wsum, [13] wsim
// plane layout: partials[(k*NSUB + sub) * ROWS_CAP + row], sub = cb*4 + wn*2 + q
#define NSUB 32                 // 8 col-blocks x 2 wn-halves x 2 q-halves

typedef __attribute__((ext_vector_type(8))) int   int8v;
typedef __attribute__((ext_vector_type(16))) float f32x16;

__device__ __forceinline__ float wave_sum_f(float v) {
#pragma unroll
  for (int off = 32; off >= 1; off >>= 1) v += __shfl_xor(v, off, 64);
  return v;
}

__device__ __forceinline__ int pack4(float a, float b, float c, float d) {
  int p = __builtin_amdgcn_cvt_pk_fp8_f32(a, b, 0, false);
  p = __builtin_amdgcn_cvt_pk_fp8_f32(c, d, p, true);
  return p;
}

__device__ __forceinline__ void gload16(const unsigned char* g, unsigned char* l) {
  __builtin_amdgcn_global_load_lds(
      (const __attribute__((address_space(1))) unsigned int*)g,
      (__attribute__((address_space(3))) unsigned int*)l, 16, 0, 0);
}

// branchless sorted-descending top-10 insert: 1 fmax + 9 med3
__device__ __forceinline__ void ins10(float* t, float v) {
#pragma unroll
  for (int i = 9; i >= 1; --i) t[i] = __builtin_amdgcn_fmed3f(v, t[i - 1], t[i]);
  t[0] = fmaxf(t[0], v);
}

// ---------------------------------------------------------------- conv + count + bitmask
// Blocks [0, NGROUP_A): 64 enhanced rows -> A tiled fp8 (LDS transpose).
// Blocks [NGROUP_A, +NGROUP_B): 64 prompt rows -> B tiled fp8.
// Blocks [NGROUP_A+NGROUP_B, +NCOUNT): class-count partial sums (atomic).
// Blocks [NGROUP_A+NGROUP_B+NCOUNT, +NBITS): label bitmask (32 u32 per row).
__global__ __launch_bounds__(256) void conv_kernel(const float* __restrict__ img,
                                                   const float* __restrict__ prompts,
                                                   const float* __restrict__ mem,
                                                   const int* __restrict__ memptr,
                                                   unsigned char* __restrict__ A,
                                                   unsigned char* __restrict__ B,
                                                   const int* __restrict__ labels,
                                                   const int* __restrict__ mlabels,
                                                   int* __restrict__ counts,
                                                   unsigned* __restrict__ bitmask) {
  const int blk = blockIdx.x;
  const int t = threadIdx.x;
  const int lane = t & 63;
  const int wid = t >> 6;
  const int nrows = BN + memptr[0];
  const int padded = (nrows + 127) & ~127;

  if (blk >= NGROUP_A + NGROUP_B + NCOUNT) {   // ---- bitmask section
    const int bi = blk - (NGROUP_A + NGROUP_B + NCOUNT);
    const int rowBase = bi * 64;
    if (rowBase >= padded) return;
    for (int i = 0; i < 16; ++i) {
      const int row = rowBase + wid * 16 + i;
      if (row >= padded) continue;
      unsigned bits = 0;
      if (row < nrows) {
        const int* lr = (row < BN) ? labels + (size_t)row * CC
                                   : mlabels + (size_t)(row - BN) * CC;
        const int cbase = lane * 16;
#pragma unroll
        for (int g = 0; g < 4; ++g) {
          int c = cbase + g * 4;
          int4 l4;
          if (c + 3 < CC) l4 = *(const int4*)(lr + c);
          else {
            l4.x = (c < CC) ? lr[c] : 0;
            l4.y = (c + 1 < CC) ? lr[c + 1] : 0;
            l4.z = (c + 2 < CC) ? lr[c + 2] : 0;
            l4.w = (c + 3 < CC) ? lr[c + 3] : 0;
          }
          unsigned m = 0;
          if (l4.x > 0) m |= 1u;
          if (l4.y > 0) m |= 2u;
          if (l4.z > 0) m |= 4u;
          if (l4.w > 0) m |= 8u;
          bits |= m << (g * 4);
        }
      }
      // lane l holds bits for cols [l*16, l*16+16): pair into 32-bit words
      unsigned pair = __shfl_xor(bits, 1, 64);
      if (!(lane & 1)) bitmask[(size_t)row * 32 + (lane >> 1)] = bits | (pair << 16);
    }
    return;
  }

  if (blk >= NGROUP_A + NGROUP_B) {            // ---- count section
    const int ci = blk - (NGROUP_A + NGROUP_B);
    const int c = (ci & 3) * 256 + t;
    if (c >= CC) return;
    const int b0 = (ci >> 2) * 32;
    int s = 0;
#pragma unroll
    for (int b = 0; b < 32; ++b) s += labels[(size_t)(b0 + b) * CC + c];
    atomicAdd(&counts[c], s);
    return;
  }

  // ---- transpose-convert section (64-row group)
  __shared__ unsigned char tile[65536];        // 64 kc-stripes x 1024 B

  const bool isB = (blk >= NGROUP_A);
  const int g = isB ? (blk - NGROUP_A) : blk;
  const int rowBase = g * 64;
  if (!isB && rowBase >= padded) return;       // never read by gemm

  unsigned char* dstBase = (isB ? B : A)
      + (size_t)(rowBase >> 7) * 131072 + (size_t)(rowBase & 64) * 16;

  for (int i = 0; i < 16; ++i) {
    const int r = wid * 16 + i;                // row slot within group
    const int row = rowBase + r;
    const float* src = nullptr;
    float esc = 1.0f;
    bool needNorm = false;
    if (isB) {
      if (row < CC) { src = prompts + (size_t)row * DD; needNorm = true; esc = 10.0f; }
    } else {
      if (row < BN)         { src = img + (size_t)row * DD; needNorm = true; }
      else if (row < nrows) { src = mem + (size_t)(row - BN) * DD; }
    }
    int4 o = {0, 0, 0, 0};
    if (src) {
      const float4* s4 = (const float4*)src + lane * 4;   // 64B per lane (k = lane*16..)
      float4 a = s4[0], b = s4[1], c = s4[2], d = s4[3];
      float sc = esc;
      if (needNorm) {
        float ss = a.x * a.x + a.y * a.y + a.z * a.z + a.w * a.w
                 + b.x * b.x + b.y * b.y + b.z * b.z + b.w * b.w
                 + c.x * c.x + c.y * c.y + c.z * c.z + c.w * c.w
                 + d.x * d.x + d.y * d.y + d.z * d.z + d.w * d.w;
        ss = wave_sum_f(ss);
        sc = esc * rsqrtf(ss + 1e-24f);
      }
      o.x = pack4(a.x * sc, a.y * sc, a.z * sc, a.w * sc);
      o.y = pack4(b.x * sc, b.y * sc, b.z * sc, b.w * sc);
      o.z = pack4(c.x * sc, c.y * sc, c.z * sc, c.w * sc);
      o.w = pack4(d.x * sc, d.y * sc, d.z * sc, d.w * sc);
    }
    // stripe kc = lane, rotated slot (r+kc)&63 -> distinct chunks per lane
    *(int4*)(tile + lane * 1024 + (((r + lane) & 63) << 4)) = o;
  }
  __syncthreads();

#pragma unroll
  for (int p = 0; p < 16; ++p) {
    const int ochunk = p * 256 + t;            // kc = ochunk>>6 (wave-uniform), rl = lane
    const int kc = ochunk >> 6;
    const int rl = ochunk & 63;
    int4 v = *(const int4*)(tile + kc * 1024 + (((rl + kc) & 63) << 4));
    *(int4*)(dstBase + (size_t)kc * 2048 + rl * 16) = v;   // 1KB contiguous per wave
  }
}

// ---------------------------------------------------------------- fused MX-fp8 GEMM + epilogue
// 128x128 tile, 512 threads (8 waves as 4 row-groups x 2 col-groups; wave = 32x64).
// acc[2]x16 = 32 VGPR per thread (was 64) -> low pressure WITHOUT launch-bounds
// coercion (R5 lesson: forced caps spill). Double-buffered LDS, 2-phase schedule:
// stage(next) issued BEFORE compute(cur), single barrier per K-step.
// OPERAND-SWAPPED MFMA: sim row = lane&31 -> epilogue is register-local.
__global__ __launch_bounds__(512) void gemm_fused(
    const unsigned char* __restrict__ A, const unsigned char* __restrict__ Bm,
    const unsigned* __restrict__ bitmask, const int* __restrict__ counts,
    const int* __restrict__ memptr, float* __restrict__ partials) {
  const int f = blockIdx.x;
  const int x = f & 7;
  const int s = f >> 3;
  const int cb = s & 7;
  const int rt = (s >> 3) * 8 + x;             // same-rt blocks share an XCD (f%8)

  const int nrows = BN + memptr[0];
  const int row0 = rt * 128;
  if (row0 >= nrows) return;
  const int c0 = cb * 128;

  __shared__ unsigned char As[2][16384];
  __shared__ unsigned char Bs[2][16384];
  __shared__ unsigned posbits[128][4];         // bit c: label(row, c0+c) > 0
  __shared__ float wcol[128];                  // normalized class weights for our cols
  __shared__ float wpart[8];

  const int t = threadIdx.x;                   // 0..511
  const int lane = t & 63;
  const int wid = t >> 6;                      // 0..7
  const int wm = (wid >> 1) * 32;              // 4 row groups of 32
  const int wn = (wid & 1) * 64;               // 2 col groups of 64
  const int q = lane >> 5;
  const int rr = lane & 31;

  const unsigned char* gaT = A + (size_t)row0 * DD;   // row0 multiple of 128
  const unsigned char* gbT = Bm + (size_t)c0 * DD;

  // stage k-step 0 into buffer 0 (issued first; latency hides under preamble)
#pragma unroll
  for (int p = 0; p < 2; ++p) {
    gload16(gaT + p * 8192 + t * 16, As[0] + p * 8192 + t * 16);
    gload16(gbT + p * 8192 + t * 16, Bs[0] + p * 8192 + t * 16);
  }

  // ---------- preamble: class weights (global normalizer) + bitmask load
  {
    float wv[2];
    float accw = 0.f;
#pragma unroll
    for (int i = 0; i < 2; ++i) {
      int c = t + i * 512;
      float w = 0.f;
      if (c < CC) {
        float cnt = (float)counts[c];
        float en = 1.0f - expf(cnt * logf(0.999f));   // 1 - BETA^cnt
        w = (1.0f - 0.999f) / (en + 1e-8f);
      }
      wv[i] = w;
      accw += w;
    }
    float sw = wave_sum_f(accw);
    if (lane == 0) wpart[wid] = sw;
    if (t < 128) {
      const int4 bm = *(const int4*)(bitmask + (size_t)(row0 + t) * 32 + cb * 4);
      posbits[t][0] = bm.x; posbits[t][1] = bm.y;
      posbits[t][2] = bm.z; posbits[t][3] = bm.w;
    }
    __syncthreads();                           // wpart/posbits visible; also drains stage 0
    float tot = 0.f;
#pragma unroll
    for (int i = 0; i < 8; ++i) tot += wpart[i];
    float scw = (float)CC / tot;
#pragma unroll
    for (int i = 0; i < 2; ++i) {
      int c = t + i * 512;
      if (c >= c0 && c < c0 + 128) wcol[c - c0] = wv[i] * scw;
    }
  }
  // wcol writes are ordered before epilogue readers by the K-loop barriers.

  f32x16 acc[2] = {};

  // ---------- K loop: 2-phase double-buffered (stage next, compute cur, 1 barrier)
  int cur = 0;
  for (int it = 0; it < 8; ++it) {
    if (it < 7) {
      const size_t kb = (size_t)(it + 1) * 16384;   // next K-step tile offset
#pragma unroll
      for (int p = 0; p < 2; ++p) {
        gload16(gaT + kb + p * 8192 + t * 16, As[cur ^ 1] + p * 8192 + t * 16);
        gload16(gbT + kb + p * 8192 + t * 16, Bs[cur ^ 1] + p * 8192 + t * 16);
      }
    }
#pragma unroll
    for (int h = 0; h < 2; ++h) {
      const int kc = h * 4 + q * 2;
      int8v af, bfv[2];
      {
        const unsigned char* pa = As[cur] + kc * 2048 + (wm + rr) * 16;
        int4 lo4 = *(const int4*)pa;
        int4 hi4 = *(const int4*)(pa + 2048);
        af[0] = lo4.x; af[1] = lo4.y; af[2] = lo4.z; af[3] = lo4.w;
        af[4] = hi4.x; af[5] = hi4.y; af[6] = hi4.z; af[7] = hi4.w;
      }
#pragma unroll
      for (int ni = 0; ni < 2; ++ni) {
        const unsigned char* pb = Bs[cur] + kc * 2048 + (wn + ni * 32 + rr) * 16;
        int4 lo4 = *(const int4*)pb;
        int4 hi4 = *(const int4*)(pb + 2048);
        bfv[ni][0] = lo4.x; bfv[ni][1] = lo4.y; bfv[ni][2] = lo4.z; bfv[ni][3] = lo4.w;
        bfv[ni][4] = hi4.x; bfv[ni][5] = hi4.y; bfv[ni][6] = hi4.z; bfv[ni][7] = hi4.w;
      }
      // SWAPPED: B as a-operand, A as b-operand -> sim row is lane-local
#pragma unroll
      for (int ni = 0; ni < 2; ++ni)
        acc[ni] = __builtin_amdgcn_mfma_scale_f32_32x32x64_f8f6f4(
            bfv[ni], af, acc[ni], 0, 0, 0, 127, 0, 127);
    }
    __syncthreads();                           // drains next-stage vmcnt + cur ds_reads
    cur ^= 1;
  }

  // ---------- register-local epilogue: per-quadrant online softmax (1 row/lane)
  const int cl = lane & 31;
  const int rl = wm + cl;                      // local row 0..127
  const int row_g = row0 + rl;
  const int sub = cb * 4 + (wid & 1) * 2 + q;  // UNIQUE per (col-block, wn-half, q-half)

  float t10[10];
#pragma unroll
  for (int i = 0; i < 10; ++i) t10[i] = -INFINITY;
  float m = -INFINITY, ssum = 0.f, wsum = 0.f, wsim = 0.f;
#pragma unroll
  for (int ni = 0; ni < 2; ++ni) {
    const unsigned bits = posbits[rl][(wid & 1) * 2 + ni];
    f32x16 v = acc[ni];
    float pq = -INFINITY;
    unsigned pb = 0;
#pragma unroll
    for (int reg = 0; reg < 16; ++reg) {
      const int ci = (reg & 3) + 8 * (reg >> 2) + 4 * q;   // col within 32-group
      const int cg = c0 + wn + ni * 32 + ci;
      const float val = v[reg];
      const bool cvalid = (cg < CC);
      const bool pos = cvalid && ((bits >> ci) & 1u);
      if (pos) {
        float w = wcol[wn + ni * 32 + ci];
        wsum += w;
        wsim += w * val;
        pq = fmaxf(pq, val);
        pb |= 1u << reg;
      }
      ins10(t10, (cvalid && !pos) ? val : -INFINITY);
    }
    if (pb) {                                  // fold quadrant into running (m, ssum)
      float ps = 0.f;
#pragma unroll
      for (int reg = 0; reg < 16; ++reg)
        ps += expf(((pb >> reg) & 1u) ? (v[reg] - pq) : -INFINITY);
      float m2 = fmaxf(m, pq);
      ssum = ssum * expf(m - m2) + ps * expf(pq - m2);   // expf(-inf)=0 handles init
      m = m2;
    }
  }
  // write 14-float partial state (plane-major for coalesced merge reads)
  float* pp = partials + (size_t)sub * ROWS_CAP + row_g;
#pragma unroll
  for (int k = 0; k < 10; ++k) pp[(size_t)k * NSUB * ROWS_CAP] = t10[k];
  pp[(size_t)10 * NSUB * ROWS_CAP] = m;
  pp[(size_t)11 * NSUB * ROWS_CAP] = ssum;
  pp[(size_t)12 * NSUB * ROWS_CAP] = wsum;
  pp[(size_t)13 * NSUB * ROWS_CAP] = wsim;
}

// ---------------------------------------------------------------- merge partials -> block sums
// 2 lanes per row (sub 0-15 / 16-31), symmetric shfl_xor(32) combine, block-level
// reduction of (lps, valid) -> one pair per block (removes big final reduce).
__global__ __launch_bounds__(256) void merge_kernel(const float* __restrict__ partials,
                                                    const int* __restrict__ memptr,
                                                    float* __restrict__ blk_lps,
                                                    float* __restrict__ blk_val) {
  const int t = threadIdx.x;
  const int lane = t & 63;
  const int half = lane >> 5;                  // 0: subs 0-15, 1: subs 16-31
  const int row = blockIdx.x * 128 + (t >> 6) * 32 + (lane & 31);
  const int nrows = BN + memptr[0];

  float t10[10];
#pragma unroll
  for (int i = 0; i < 10; ++i) t10[i] = -INFINITY;
  float Mp = -INFINITY, psum = 0.f, wsum = 0.f, wsim = 0.f;

  if (row < nrows) {
    for (int sub = half * 16; sub < half * 16 + 16; ++sub) {
      const float* pp = partials + (size_t)sub * ROWS_CAP + row;
#pragma unroll
      for (int j = 0; j < 10; ++j) {
        float v = pp[(size_t)j * NSUB * ROWS_CAP];
        ins10(t10, v);
      }
      float pm = pp[(size_t)10 * NSUB * ROWS_CAP];
      float ps = pp[(size_t)11 * NSUB * ROWS_CAP];
      wsum += pp[(size_t)12 * NSUB * ROWS_CAP];
      wsim += pp[(size_t)13 * NSUB * ROWS_CAP];
      if (ps > 0.f) {                          // pm finite here
        float m2 = fmaxf(Mp, pm);
        psum = psum * expf(Mp - m2) + ps * expf(pm - m2);
        Mp = m2;
      }
    }
  }

  // symmetric pairwise combine across the half-split (snapshot partner first!)
  float o10[10];
#pragma unroll
  for (int j = 0; j < 10; ++j) o10[j] = __shfl_xor(t10[j], 32, 64);
#pragma unroll
  for (int j = 0; j < 10; ++j) ins10(t10, o10[j]);
  float pm2 = __shfl_xor(Mp, 32, 64);
  float ps2 = __shfl_xor(psum, 32, 64);
  float w2  = __shfl_xor(wsum, 32, 64);
  float ws2 = __shfl_xor(wsim, 32, 64);
  if (ps2 > 0.f) {
    float m2 = fmaxf(Mp, pm2);
    psum = psum * expf(Mp - m2) + ps2 * expf(pm2 - m2);
    Mp = m2;
  }
  wsum += w2;
  wsim += ws2;

  float cl = 0.f, cv = 0.f;                    // per-thread contribution (half 0 only)
  if (row < nrows && half == 0) {
    const float M = fmaxf(Mp, t10[0]);         // finite: every row has >=10 negatives
    float esum = 0.f;
#pragma unroll
    for (int j = 0; j < 10; ++j) esum += expf(t10[j] - M);
    if (psum > 0.f) esum += psum * expf(Mp - M);
    const float lse = M + logf(esum);
    const bool valid = (wsum > 0.f);
    const float lps = valid ? (wsum * lse - wsim) / (wsum + 1e-8f) : 0.f;
    const float mult = (row < BN) ? 2.f : 1.f; // image rows appear twice in enhanced set
    cl = mult * lps;
    cv = valid ? mult : 0.f;
  }
  cl = wave_sum_f(cl);
  cv = wave_sum_f(cv);
  __shared__ float p1[4], p2[4];
  if (lane == 0) { p1[t >> 6] = cl; p2[t >> 6] = cv; }
  __syncthreads();
  if (t == 0) {
    blk_lps[blockIdx.x] = p1[0] + p1[1] + p1[2] + p1[3];
    blk_val[blockIdx.x] = p2[0] + p2[1] + p2[2] + p2[3];
  }
}

// ---------------------------------------------------------------- final reduce (256 values)
__global__ __launch_bounds__(256) void reduce_kernel(const float* __restrict__ blk_lps,
                                                     const float* __restrict__ blk_val,
                                                     float* __restrict__ out) {
  const int t = threadIdx.x;
  float a = wave_sum_f(blk_lps[t]);
  float b = wave_sum_f(blk_val[t]);
  __shared__ float p1[4], p2[4];
  if ((t & 63) == 0) { p1[t >> 6] = a; p2[t >> 6] = b; }
  __syncthreads();
  if (t == 0) {
    float A = p1[0] + p1[1] + p1[2] + p1[3];
    float B = p2[0] + p2[1] + p2[2] + p2[3];
    out[0] = A / fmaxf(B, 1.0f);
  }
}

// ---------------------------------------------------------------- launcher
extern "C" void kernel_launch(void* const* d_in, const int* in_sizes, int n_in,
                              void* d_out, int out_size, void* d_ws, size_t ws_size,
                              hipStream_t stream) {
  const float* img     = (const float*)d_in[0];
  const float* prompts = (const float*)d_in[1];
  const int*   labels  = (const int*)d_in[2];
  const float* mem     = (const float*)d_in[3];
  const int*   mlabels = (const int*)d_in[4];
  const int*   memptr  = (const int*)d_in[5];
  float* out = (float*)d_out;
  char* ws = (char*)d_ws;

  int*      counts  = (int*)(ws + 0);            // 1000 ints (8 KiB reserved)
  float*    blk_lps = (float*)(ws + 8192);       // 256 f
  float*    blk_val = (float*)(ws + 12288);      // 256 f
  unsigned* bitmask = (unsigned*)(ws + 270336);  // 32768 x 32 u32 = 4 MiB
  unsigned char* Bf8 = (unsigned char*)(ws + 4464640);   // 1024x1024 fp8 = 1 MiB
  unsigned char* Af8 = (unsigned char*)(ws + 5513216);   // 32768x1024 fp8 = 32 MiB
  float* partials = (float*)(ws + 5513216 + (size_t)ROWS_CAP * DD);  // 14*32*32768*4 = 58.7 MB

  hipMemsetAsync(ws, 0, 4096, stream);      // zero counts

  conv_kernel<<<NGROUP_A + NGROUP_B + NCOUNT + NBITS, 256, 0, stream>>>(
      img, prompts, mem, memptr, Af8, Bf8, labels, mlabels, counts, bitmask);

  gemm_fused<<<8 * (ROWS_CAP / 128), 512, 0, stream>>>(
      Af8, Bf8, bitmask, counts, memptr, partials);

  merge_kernel<<<ROWS_CAP / 128, 256, 0, stream>>>(partials, memptr, blk_lps, blk_val);

  reduce_kernel<<<1, 256, 0, stream>>>(blk_lps, blk_val, out);
}